// Round 1
// baseline (554.173 us; speedup 1.0000x reference)
//
#include <hip/hip_runtime.h>

// OSQP batched ADMM, B=256 N=128 M=192, 400 iters.
// Design: one block (512 thr) per batch per CU. Schur-complement reformulation:
//   M = P + sI + rho*A^T A (SPD);  W = M^-1 A^T;  c = M^-1 q
//   iterate: xt = W s - c ; w = A xt ; x += ... ; v = a*w+(1-a)z + y/rho ;
//            z = clip(v,l,u) ; y = rho*(v-z) ; s = rho*z - y
// W and A live in VGPRs (48 + 64 floats/thread), vectors in LDS, state in
// producer-lane regs. DPP (VALU) cross-lane reductions. 2 barriers/iter.
// LDS: single 64 KiB buffer, phase-aliased (A-chunk stage -> S -> GJ bufs -> s/xt).

#define Nn 128
#define Mm 192
constexpr float RHO_    = 0.1f;
constexpr float RHOINV_ = 10.0f;
constexpr float SIGMA_  = 1e-6f;
constexpr float ALPHA_  = 1.6f;
constexpr int   NITERS_ = 400;

template<int CTRL>
__device__ __forceinline__ float dpp_add(float x) {
  int y = __builtin_amdgcn_update_dpp(0, __float_as_int(x), CTRL, 0xF, 0xF, false);
  return x + __int_as_float(y);
}
// sum across aligned 16-lane group (DPP row): row_ror 1,2,4,8
__device__ __forceinline__ float red16(float x) {
  x = dpp_add<0x121>(x); x = dpp_add<0x122>(x);
  x = dpp_add<0x124>(x); x = dpp_add<0x128>(x);
  return x;
}
// sum across aligned 8-lane group: quad_perm xor1 (0xB1), xor2 (0x4E), half_mirror
__device__ __forceinline__ float red8(float x) {
  x = dpp_add<0x0B1>(x); x = dpp_add<0x04E>(x); x = dpp_add<0x141>(x);
  return x;
}

// xt padded layout: +4 floats every 16 -> bank-conflict-free & 16B-aligned per cg2
#define XTI(r) ((r) + 4*((r)>>4))

#define D12(G) (G[0]*s0.x+G[1]*s0.y+G[2]*s0.z+G[3]*s0.w \
              + G[4]*s1.x+G[5]*s1.y+G[6]*s1.z+G[7]*s1.w \
              + G[8]*s2.x+G[9]*s2.y+G[10]*s2.z+G[11]*s2.w)
#define D16(F) (F[0]*x0v.x+F[1]*x0v.y+F[2]*x0v.z+F[3]*x0v.w \
              + F[4]*x1v.x+F[5]*x1v.y+F[6]*x1v.z+F[7]*x1v.w \
              + F[8]*x2v.x+F[9]*x2v.y+F[10]*x2v.z+F[11]*x2v.w \
              + F[12]*x3v.x+F[13]*x3v.y+F[14]*x3v.z+F[15]*x3v.w)

__global__ void __launch_bounds__(512, 2)
osqp_kernel(const float* __restrict__ Pg, const float* __restrict__ qg,
            const float* __restrict__ Ag, const float* __restrict__ lg,
            const float* __restrict__ ug, float* __restrict__ outg)
{
  __shared__ float smem[16384];   // 64 KiB, aliased across phases
  const int t = threadIdx.x;
  const int b = blockIdx.x;
  const float* __restrict__ Pb = Pg + (size_t)b*Nn*Nn;
  const float* __restrict__ qb = qg + (size_t)b*Nn;
  const float* __restrict__ Ab = Ag + (size_t)b*Mm*Nn;
  const float* __restrict__ lb = lg + (size_t)b*Mm;
  const float* __restrict__ ub = ug + (size_t)b*Mm;

  //================ Phase A: S = P + sigma*I + rho * A^T A (S in LDS) ================
  {
    const int ar = t & 31;   // 32 row-groups of 4 rows
    const int bc = t >> 5;   // 16 col-groups of 8 cols
    float acc[4][8];
    #pragma unroll
    for (int a=0;a<4;a++)
      #pragma unroll
      for (int j=0;j<8;j++) acc[a][j]=0.f;

    for (int c=0;c<6;c++) {
      __syncthreads();
      { // stage A rows [32c,32c+32) x 128 into smem[0:4096]
        const float4* src = (const float4*)(Ab + c*32*Nn);
        float4* dst = (float4*)smem;
        dst[t]     = src[t];
        dst[t+512] = src[t+512];
      }
      __syncthreads();
      #pragma unroll 2
      for (int m=0;m<32;m++) {
        const float4 ra  = *(const float4*)&smem[m*Nn + 4*ar];
        const float4 cb0 = *(const float4*)&smem[m*Nn + 8*bc];
        const float4 cb1 = *(const float4*)&smem[m*Nn + 8*bc + 4];
        const float rv[4] = {ra.x, ra.y, ra.z, ra.w};
        const float cv[8] = {cb0.x,cb0.y,cb0.z,cb0.w,cb1.x,cb1.y,cb1.z,cb1.w};
        #pragma unroll
        for (int a=0;a<4;a++)
          #pragma unroll
          for (int j=0;j<8;j++) acc[a][j] += rv[a]*cv[j];
      }
    }
    __syncthreads();
    #pragma unroll
    for (int a=0;a<4;a++) {
      const int i = 4*ar + a;
      #pragma unroll
      for (int j=0;j<8;j++) {
        const int jj = 8*bc + j;
        float v = Pb[i*Nn + jj] + RHO_*acc[a][j];
        if (i == jj) v += SIGMA_;
        smem[i*Nn + jj] = v;
      }
    }
    __syncthreads();
  }

  //================ Phase B: S <- S^-1, in-place Gauss-Jordan (SPD, no pivot) ========
  // rows cached in registers; only pivot row + pivot column round-trip LDS.
  {
    const int irow = t >> 2;   // 0..127
    const int qq   = t & 3;    // col quarter [32qq, 32qq+32)
    float rr[32];
    #pragma unroll
    for (int j=0;j<32;j++) rr[j] = smem[irow*Nn + 32*qq + j];
    __syncthreads();
    float* rowk = smem;        // [128]  (aliases stale S rows 0..1)
    float* fcol = smem + Nn;   // [128]
    for (int k0=0;k0<4;k0++) {
      #pragma unroll            // full unroll: rr[kk] index must be static
      for (int kk=0;kk<32;kk++) {
        const int k = 32*k0 + kk;
        if (irow == k) {
          #pragma unroll
          for (int j=0;j<32;j++) rowk[32*qq+j] = rr[j];
        }
        if (qq == k0) fcol[irow] = rr[kk];
        __syncthreads();
        const float pinv = 1.0f / rowk[k];
        if (irow == k) {
          #pragma unroll
          for (int j=0;j<32;j++) rr[j] *= pinv;
          if (qq == k0) rr[kk] = pinv;
        } else {
          const float gfac = fcol[irow] * pinv;
          #pragma unroll
          for (int j=0;j<32;j++) rr[j] -= gfac * rowk[32*qq+j];
          if (qq == k0) rr[kk] = -gfac;
        }
        __syncthreads();
      }
    }
    #pragma unroll
    for (int j=0;j<32;j++) smem[irow*Nn + 32*qq + j] = rr[j];  // write Minv back
  }
  __syncthreads();

  //================ Phase C: extract W (regs), c, A-regs, state ======================
  const int rg  = t >> 4, cg  = t & 15;  // stage-1: rows 4rg+a, cols 12cg+ii
  const int rg2 = t >> 3, cg2 = t & 7;   // stage-2: rows 4rg2+a, cols 16cg2+v

  float g[4][12];                        // W[4rg+a][12cg+ii] = sum_k Minv[r][k]*A[j][k]
  #pragma unroll
  for (int a=0;a<4;a++)
    #pragma unroll
    for (int ii=0;ii<12;ii++) g[a][ii]=0.f;
  for (int k4=0;k4<32;k4++) {
    float4 mv0 = *(const float4*)&smem[(4*rg+0)*Nn + 4*k4];
    float4 mv1 = *(const float4*)&smem[(4*rg+1)*Nn + 4*k4];
    float4 mv2 = *(const float4*)&smem[(4*rg+2)*Nn + 4*k4];
    float4 mv3 = *(const float4*)&smem[(4*rg+3)*Nn + 4*k4];
    #pragma unroll
    for (int ii=0;ii<12;ii++) {
      const int j = 12*cg + ii;
      const float4 av = *(const float4*)&Ab[j*Nn + 4*k4];
      g[0][ii] += mv0.x*av.x + mv0.y*av.y + mv0.z*av.z + mv0.w*av.w;
      g[1][ii] += mv1.x*av.x + mv1.y*av.y + mv1.z*av.z + mv1.w*av.w;
      g[2][ii] += mv2.x*av.x + mv2.y*av.y + mv2.z*av.z + mv2.w*av.w;
      g[3][ii] += mv3.x*av.x + mv3.y*av.y + mv3.z*av.z + mv3.w*av.w;
    }
  }

  float c_reg = 0.f;                     // c[r] = Minv[r,:].q  (used by cg<4 lanes)
  {
    const int r = 4*rg + (cg & 3);
    for (int k4=0;k4<32;k4++) {
      const float4 mvv = *(const float4*)&smem[r*Nn + 4*k4];
      const float4 qv  = *(const float4*)&qb[4*k4];
      c_reg += mvv.x*qv.x + mvv.y*qv.y + mvv.z*qv.z + mvv.w*qv.w;
    }
  }

  float af[4][16];                       // A[4rg2+a][16cg2+v], threads < 384
  #pragma unroll
  for (int a=0;a<4;a++)
    #pragma unroll
    for (int v=0;v<16;v++) af[a][v]=0.f;
  if (t < 384) {
    #pragma unroll
    for (int a=0;a<4;a++)
      #pragma unroll
      for (int v4=0;v4<4;v4++) {
        const float4 tmp = *(const float4*)&Ab[(4*rg2+a)*Nn + 16*cg2 + 4*v4];
        af[a][4*v4+0]=tmp.x; af[a][4*v4+1]=tmp.y; af[a][4*v4+2]=tmp.z; af[a][4*v4+3]=tmp.w;
      }
  }

  float zreg=0.f, yreg=0.f, lreg=0.f, ureg=0.f;
  if (t < 384) {
    const int m = 4*rg2 + (cg2 & 3);
    lreg = lb[m]; ureg = ub[m];
  }

  __syncthreads();                       // Minv reads done; smem reused below
  float* sbuf = smem;                    // s[192]
  float* xtb  = smem + 256;              // xt, padded layout, 160 floats
  if (t < 192) sbuf[t] = 0.f;            // s0 = rho*z0 - y0 = 0
  __syncthreads();

  //================ Main ADMM loop ===================================================
  const int  prow = 4*rg + (cg & 3);
  const bool isp1 = (cg < 4);
  const int  pm   = 4*rg2 + (cg2 & 3);
  const bool isp2 = (t < 384) && (cg2 < 4);
  float xreg = 0.f;
  const float4* s4 = (const float4*)(sbuf + 12*cg);  // 48B offset: 16B-aligned
  const float*  xtr = xtb + 20*cg2;                  // contiguous 16, bank-clean

  #pragma unroll 1
  for (int it=0; it<NITERS_; it++) {
    // ---- stage 1: xt = W s - c ; x update (producer lanes) ----
    const float4 s0 = s4[0], s1 = s4[1], s2 = s4[2];
    float a0 = D12(g[0]);
    float a1 = D12(g[1]);
    float a2 = D12(g[2]);
    float a3 = D12(g[3]);
    a0 = red16(a0); a1 = red16(a1); a2 = red16(a2); a3 = red16(a3);
    if (isp1) {
      const float accv = (cg==0)?a0 : (cg==1)?a1 : (cg==2)?a2 : a3;
      const float xtv  = accv - c_reg;
      xtb[XTI(prow)] = xtv;
      xreg = ALPHA_*xtv + (1.f-ALPHA_)*xreg;
    }
    __syncthreads();
    // ---- stage 2: w = A xt ; z,y,s update (producer lanes) ----
    if (t < 384) {
      const float4 x0v = *(const float4*)(xtr+0);
      const float4 x1v = *(const float4*)(xtr+4);
      const float4 x2v = *(const float4*)(xtr+8);
      const float4 x3v = *(const float4*)(xtr+12);
      float b0 = D16(af[0]);
      float b1 = D16(af[1]);
      float b2 = D16(af[2]);
      float b3 = D16(af[3]);
      b0 = red8(b0); b1 = red8(b1); b2 = red8(b2); b3 = red8(b3);
      if (isp2) {
        const float w  = (cg2==0)?b0 : (cg2==1)?b1 : (cg2==2)?b2 : b3;
        const float zc = ALPHA_*w + (1.f-ALPHA_)*zreg;
        const float vv = zc + yreg*RHOINV_;
        const float zn = fminf(fmaxf(vv, lreg), ureg);
        yreg = RHO_*(vv - zn);
        zreg = zn;
        sbuf[pm] = RHO_*zreg - yreg;
      }
    }
    __syncthreads();
  }

  if (isp1) outg[(size_t)b*Nn + prow] = xreg;
}

extern "C" void kernel_launch(void* const* d_in, const int* in_sizes, int n_in,
                              void* d_out, int out_size, void* d_ws, size_t ws_size,
                              hipStream_t stream) {
  const float* P = (const float*)d_in[0];
  const float* q = (const float*)d_in[1];
  const float* A = (const float*)d_in[2];
  const float* l = (const float*)d_in[3];
  const float* u = (const float*)d_in[4];
  (void)in_sizes; (void)n_in; (void)d_ws; (void)ws_size; (void)out_size;
  osqp_kernel<<<256, 512, 0, stream>>>(P, q, A, l, u, (float*)d_out);
}